// Round 11
// baseline (398.085 us; speedup 1.0000x reference)
//
#include <hip/hip_runtime.h>
#include <hip/hip_bf16.h>

// ---------------------------------------------------------------------------
// GCN-VGAE encoder. Round 11: slab-pinned gather, wave-cooperative edges.
//  R10 post-mortem: slab pinning killed HBM fetch (95->28MB) but 16-lane/node
//  structure was issue-bound (VALU 38%, max-of-4-degrees divergence).
//  Now: one node per 64-lane wave; lanes = 4 edge-groups x 16 channel-words.
//  Group lg takes edges k+lg step 4 (4 edges in flight, trip ~ deg/4), then
//  cross-group reduce via 2x shfl_xor. Slab layout [4][N][32ch] kept: q =
//  blockIdx&3 -> round-robin XCD dispatch pins each 3.2MB slab in one L2.
// Rest as R9/R10: two-pass bucketed CSR sort, MFMA GEMMs, packed 4B CSR,
// fused BN (last-block ticket), bf16 activations.
// ---------------------------------------------------------------------------

using short8 = __attribute__((ext_vector_type(8))) short;
using f32x4  = __attribute__((ext_vector_type(4))) float;

static __device__ __forceinline__ unsigned short f2bf(float f) {
    __hip_bfloat16 h = __float2bfloat16(f);
    return *reinterpret_cast<unsigned short*>(&h);
}
static __device__ __forceinline__ float bf_lo(unsigned int u) {
    return __uint_as_float(u << 16);
}
static __device__ __forceinline__ float bf_hi(unsigned int u) {
    return __uint_as_float(u & 0xffff0000u);
}
static __device__ __forceinline__ float bf2f(unsigned short u) {
    return __uint_as_float((unsigned int)u << 16);
}

__global__ __launch_bounds__(256)
void deg_count(const int* __restrict__ ei, int* __restrict__ cnt, int E_) {
    int e = blockIdx.x * 256 + threadIdx.x;
    if (e < E_) atomicAdd(&cnt[ei[E_ + e]], 1);   // row 1 = dst
}

// ---- hierarchical exclusive scan (dinv fused): cnt[0..n) -> rowptr[0..n] ----
__global__ __launch_bounds__(1024)
void scan_blocks(const int* __restrict__ cnt, float* __restrict__ dinv,
                 int* __restrict__ rowptr, int* __restrict__ partials, int n) {
    __shared__ int ls[1024];
    int tid = threadIdx.x;
    int i = blockIdx.x * 1024 + tid;
    int v = (i < n) ? cnt[i] : 0;
    if (i < n) dinv[i] = rsqrtf((float)v + 1.0f);
    ls[tid] = v;
    __syncthreads();
    #pragma unroll
    for (int off = 1; off < 1024; off <<= 1) {
        int t = (tid >= off) ? ls[tid - off] : 0;
        __syncthreads();
        ls[tid] += t;
        __syncthreads();
    }
    if (i < n) rowptr[i] = ls[tid] - v;           // local exclusive
    if (tid == 1023) partials[blockIdx.x] = ls[1023];
}

__global__ __launch_bounds__(1024)
void scan_partials(int* __restrict__ partials, int* __restrict__ rowptr_n,
                   int nb) {
    __shared__ int ls[1024];
    int tid = threadIdx.x;
    int v = (tid < nb) ? partials[tid] : 0;
    ls[tid] = v;
    __syncthreads();
    #pragma unroll
    for (int off = 1; off < 1024; off <<= 1) {
        int t = (tid >= off) ? ls[tid - off] : 0;
        __syncthreads();
        ls[tid] += t;
        __syncthreads();
    }
    if (tid < nb) partials[tid] = ls[tid] - v;    // exclusive block offsets
    if (tid == 1023) *rowptr_n = ls[1023];        // rowptr[n] = E
}

// add block offsets; also seed per-bucket claim cursors gcursor[b]=rowptr[b*128]
__global__ __launch_bounds__(256)
void scan_add(int* __restrict__ rowptr, int* __restrict__ gcursor,
              const int* __restrict__ partials, int n) {
    int i = blockIdx.x * 256 + threadIdx.x;
    if (i < n) {
        int v = rowptr[i] + partials[i >> 10];
        rowptr[i] = v;
        if ((i & 127) == 0) gcursor[i >> 7] = v;
    }
}

// ---- CSR build pass 1: bin edges into 128-node buckets ----
#define BCHUNK 4096
__global__ __launch_bounds__(256)
void bin_edges(const int* __restrict__ ei, const float* __restrict__ dinv,
               int* __restrict__ gcursor, uint2* __restrict__ binned, int E_) {
    __shared__ int hist[512];
    __shared__ int gbase[512];
    __shared__ int cur[512];
    const int tid = threadIdx.x;
    const int e0 = blockIdx.x * BCHUNK;

    #pragma unroll
    for (int q = 0; q < 2; ++q) hist[q * 256 + tid] = 0;
    __syncthreads();

    for (int i = tid; i < BCHUNK; i += 256) {
        int e = e0 + i;
        if (e < E_) atomicAdd(&hist[ei[E_ + e] >> 7], 1);
    }
    __syncthreads();

    #pragma unroll
    for (int q = 0; q < 2; ++q) {
        int b = q * 256 + tid;
        int c = hist[b];
        gbase[b] = c ? atomicAdd(&gcursor[b], c) : 0;
        cur[b] = 0;
    }
    __syncthreads();

    for (int i = tid; i < BCHUNK; i += 256) {
        int e = e0 + i;
        if (e >= E_) continue;
        int s = ei[e], d = ei[E_ + e];
        float coef = dinv[s] * dinv[d];
        unsigned int cb = (__float_as_uint(coef) + 0x8000u) >> 16;  // RN bf16
        unsigned int entry = ((unsigned int)s << 15) | (cb & 0x7fffu);
        int b = d >> 7;
        int p = gbase[b] + atomicAdd(&cur[b], 1);
        binned[p] = make_uint2(entry, (unsigned int)(d & 127));
    }
}

// ---- CSR build pass 2: exact placement within each bucket ----
__global__ __launch_bounds__(256)
void place_edges(const uint2* __restrict__ binned, const int* __restrict__ rowptr,
                 unsigned int* __restrict__ csr, int n) {
    __shared__ int cur[128];
    const int tid = threadIdx.x;
    const int n0 = blockIdx.x * 128;
    const int nn = min(128, n - n0);
    if (tid < nn) cur[tid] = rowptr[n0 + tid];
    __syncthreads();
    const int beg = rowptr[n0];
    const int end = rowptr[min(n0 + 128, n)];
    for (int i = beg + tid; i < end; i += 256) {
        uint2 v = binned[i];
        int p = atomicAdd(&cur[v.y], 1);
        csr[p] = v.x;
    }
}

// ---------------------------------------------------------------------------
// MFMA GEMM: Y = act(X) @ W, K=128. Y is QUARTER-MAJOR bf16 [4][N][32].
// XBF: X is quarter-major bf16; else f32 row-major [N][128].
// ---------------------------------------------------------------------------
template<bool XBF, bool FUSE_BN, bool SPLIT_W>
__global__ __launch_bounds__(256)
void gemm_mfma(const void* __restrict__ Xv, const float* __restrict__ Wa,
               const float* __restrict__ Wb, const float* __restrict__ sc,
               const float* __restrict__ sh, unsigned short* __restrict__ Y,
               int nRows) {
    __shared__ unsigned short wt[128 * 128];  // [c][k] bf16, k XOR-swizzled

    const int tid = threadIdx.x;

    #pragma unroll
    for (int it = 0; it < 16; ++it) {
        int flat4 = it * 256 + tid;          // float4 index over 16384 floats
        int k  = flat4 >> 5;
        int c0 = (flat4 & 31) * 4;
        const float* srcp;
        if (!SPLIT_W) srcp = Wa + k * 128 + c0;
        else          srcp = (c0 < 64) ? (Wa + k * 64 + c0)
                                       : (Wb + k * 64 + (c0 - 64));
        float4 v = *(const float4*)srcp;
        float vv[4] = {v.x, v.y, v.z, v.w};
        #pragma unroll
        for (int j = 0; j < 4; ++j) {
            int c = c0 + j;
            wt[c * 128 + (k ^ ((c & 7) << 3))] = f2bf(vv[j]);
        }
    }
    __syncthreads();

    const int lane = tid & 63;
    const int wv   = tid >> 6;
    const int lm   = lane & 15;              // frag row (A) / col (B,D)
    const int lg   = lane >> 4;              // k-group
    const int row0 = blockIdx.x * 128 + wv * 32;

    f32x4 acc[2][8] = {};

    #pragma unroll
    for (int ks = 0; ks < 4; ++ks) {
        const int k0 = ks * 32 + lg * 8;

        short8 a[2];
        #pragma unroll
        for (int mf = 0; mf < 2; ++mf) {
            int r = row0 + mf * 16 + lm;
            if (r < nRows) {
                if (XBF) {
                    // quarter-major: slab qk = k0>>5, offset k0&31
                    const unsigned short* X = (const unsigned short*)Xv;
                    a[mf] = *(const short8*)(X +
                        ((size_t)(k0 >> 5) * nRows + r) * 32 + (k0 & 31));
                    if (FUSE_BN) {
                        float4 s0 = *(const float4*)(sc + k0);
                        float4 s1 = *(const float4*)(sc + k0 + 4);
                        float4 h0 = *(const float4*)(sh + k0);
                        float4 h1 = *(const float4*)(sh + k0 + 4);
                        float sv[8] = {s0.x, s0.y, s0.z, s0.w, s1.x, s1.y, s1.z, s1.w};
                        float hv[8] = {h0.x, h0.y, h0.z, h0.w, h1.x, h1.y, h1.z, h1.w};
                        #pragma unroll
                        for (int j = 0; j < 8; ++j) {
                            float v = bf2f((unsigned short)a[mf][j]);
                            v = fmaxf(v * sv[j] + hv[j], 0.f);
                            a[mf][j] = (short)f2bf(v);
                        }
                    }
                } else {
                    const float* xp = (const float*)Xv + (size_t)r * 128 + k0;
                    float4 p0 = *(const float4*)xp;
                    float4 p1 = *(const float4*)(xp + 4);
                    float pv[8] = {p0.x, p0.y, p0.z, p0.w, p1.x, p1.y, p1.z, p1.w};
                    #pragma unroll
                    for (int j = 0; j < 8; ++j) a[mf][j] = (short)f2bf(pv[j]);
                }
            } else {
                a[mf] = short8{};
            }
        }

        #pragma unroll
        for (int f = 0; f < 8; ++f) {
            int c = f * 16 + lm;
            short8 b = *(const short8*)&wt[c * 128 + (k0 ^ ((c & 7) << 3))];
            acc[0][f] = __builtin_amdgcn_mfma_f32_16x16x32_bf16(a[0], b, acc[0][f], 0, 0, 0);
            acc[1][f] = __builtin_amdgcn_mfma_f32_16x16x32_bf16(a[1], b, acc[1][f], 0, 0, 0);
        }
    }

    // store D quarter-major: col c -> slab c>>5, offset c&31
    #pragma unroll
    for (int mf = 0; mf < 2; ++mf) {
        #pragma unroll
        for (int reg = 0; reg < 4; ++reg) {
            int r = row0 + mf * 16 + lg * 4 + reg;
            if (r >= nRows) continue;
            #pragma unroll
            for (int f = 0; f < 8; ++f) {
                int c = f * 16 + lm;
                Y[((size_t)(c >> 5) * nRows + r) * 32 + (c & 31)] =
                    f2bf(acc[mf][f][reg]);
            }
        }
    }
}

// ---------------------------------------------------------------------------
// Slab gather, wave-cooperative: one node per 64-lane wave.
// lanes = edge-group lg (lane>>4) x channel word l16 (lane&15).
// Group lg processes edges k+lg step 4 (4 edges in flight); cross-group
// reduce via shfl_xor(16), shfl_xor(32). q = blockIdx&3 pins slab to XCD.
// TO_OUT: write f32 [z_mean N x 64 | z_log N x 64] (slabs 0,1 -> mean).
// ---------------------------------------------------------------------------
template<bool TO_OUT>
__global__ __launch_bounds__(256)
void gather_q(const unsigned short* __restrict__ M,
              const int* __restrict__ rowptr,
              const unsigned int* __restrict__ csr,
              const float* __restrict__ dinv, void* __restrict__ O, int n) {
    const int tid  = threadIdx.x;
    const int q    = blockIdx.x & 3;
    const int tile = blockIdx.x >> 2;
    const int wv   = tid >> 6;
    const int lane = tid & 63;
    const int l16  = lane & 15;             // channel word (2 bf16)
    const int lg   = lane >> 4;             // edge group 0..3
    const int node = tile * 4 + wv;
    if (node >= n) return;

    const unsigned int* slab = (const unsigned int*)M + (size_t)q * n * 16;

    float di = dinv[node];
    unsigned int su = slab[(size_t)node * 16 + l16];
    float selfc = (lg == 0) ? di * di : 0.f;
    float ax = bf_lo(su) * selfc, ay = bf_hi(su) * selfc;

    int beg = __builtin_amdgcn_readfirstlane(rowptr[node]);
    int end = __builtin_amdgcn_readfirstlane(rowptr[node + 1]);

    for (int k = beg + lg; k < end; k += 4) {
        unsigned int e = csr[k];            // same addr within group: L1 bcast
        unsigned int u = slab[(size_t)(e >> 15) * 16 + l16];
        float wgt = __uint_as_float((e & 0x7fffu) << 16);
        ax += wgt * bf_lo(u);
        ay += wgt * bf_hi(u);
    }
    // sum the 4 edge-groups (lanes differing in bits 4 and 5)
    ax += __shfl_xor(ax, 16, 64);
    ay += __shfl_xor(ay, 16, 64);
    ax += __shfl_xor(ax, 32, 64);
    ay += __shfl_xor(ay, 32, 64);

    if (lg == 0) {
        if (!TO_OUT) {
            unsigned int o = (unsigned int)f2bf(ax) | ((unsigned int)f2bf(ay) << 16);
            ((unsigned int*)O)[(size_t)q * n * 16 + (size_t)node * 16 + l16] = o;
        } else {
            float* dst = (float*)O + (size_t)(q >> 1) * n * 64 +
                         (size_t)node * 64 + (q & 1) * 32 + 2 * l16;
            *(float2*)dst = make_float2(ax, ay);
        }
    }
}

// column sums/sumsq over quarter-major bf16 H + FUSED bn_coef (last-block
// ticket). Block handles slab q = blockIdx&3.
__global__ __launch_bounds__(256)
void bn_stats(const unsigned short* __restrict__ H, float* __restrict__ stats,
              const float* __restrict__ gamma, const float* __restrict__ beta,
              float* __restrict__ sc, float* __restrict__ sh,
              unsigned int* __restrict__ ticket, int n) {
    const int tid = threadIdx.x;
    const int q   = blockIdx.x & 3;
    const int bq  = blockIdx.x >> 2;
    const int nbq = gridDim.x >> 2;
    const uint4* hq = (const uint4*)(H + (size_t)q * n * 32);
    const int total = n * 4;                      // uint4s per slab
    float s[8] = {}, qq[8] = {};
    for (int f = bq * 256 + tid; f < total; f += nbq * 256) {
        uint4 u = hq[f];                          // coalesced 4KB/block/iter
        float v[8] = {bf_lo(u.x), bf_hi(u.x), bf_lo(u.y), bf_hi(u.y),
                      bf_lo(u.z), bf_hi(u.z), bf_lo(u.w), bf_hi(u.w)};
        #pragma unroll
        for (int j = 0; j < 8; ++j) { s[j] += v[j]; qq[j] += v[j] * v[j]; }
    }
    __shared__ float ls[256][17];
    #pragma unroll
    for (int j = 0; j < 8; ++j) { ls[tid][j] = s[j]; ls[tid][8 + j] = qq[j]; }
    __syncthreads();
    if (tid < 32) {                               // 32 channels per slab
        int wg = tid >> 3, j = tid & 7;
        float S = 0.f, Q = 0.f;
        #pragma unroll
        for (int g = 0; g < 64; ++g) {
            S += ls[g * 4 + wg][j];
            Q += ls[g * 4 + wg][8 + j];
        }
        int ch = q * 32 + wg * 8 + j;
        atomicAdd(&stats[ch], S);
        atomicAdd(&stats[128 + ch], Q);
    }
    // drain ALL waves' stats atomics before publishing this block's ticket
    __syncthreads();
    __shared__ int lastFlag;
    if (tid == 0) {
        __threadfence();
        unsigned int t = atomicAdd(ticket, 1u);
        lastFlag = (t == gridDim.x - 1);
    }
    __syncthreads();
    if (lastFlag && tid < 128) {
        float Ssum = __hip_atomic_load(&stats[tid], __ATOMIC_RELAXED,
                                       __HIP_MEMORY_SCOPE_AGENT);
        float Qsum = __hip_atomic_load(&stats[128 + tid], __ATOMIC_RELAXED,
                                       __HIP_MEMORY_SCOPE_AGENT);
        float inv_n = 1.0f / (float)n;
        float mean = Ssum * inv_n;
        float var  = Qsum * inv_n - mean * mean;
        float sv = rsqrtf(var + 1e-5f) * gamma[tid];
        sc[tid] = sv;
        sh[tid] = beta[tid] - mean * sv;
    }
}

extern "C" void kernel_launch(void* const* d_in, const int* in_sizes, int n_in,
                              void* d_out, int out_size, void* d_ws, size_t ws_size,
                              hipStream_t stream) {
    const float* x    = (const float*)d_in[0];
    const int*   ei   = (const int*)d_in[1];
    const float* W0   = (const float*)d_in[2];
    const float* W1   = (const float*)d_in[3];
    const float* Wmu  = (const float*)d_in[4];
    const float* Wlog = (const float*)d_in[5];
    const float* g0   = (const float*)d_in[6];
    const float* b0   = (const float*)d_in[7];
    const float* g1   = (const float*)d_in[8];
    const float* b1   = (const float*)d_in[9];

    const int N_ = in_sizes[0] / 128;
    const int E_ = in_sizes[1] / 2;
    float* out = (float*)d_out;

    char* w = (char*)d_ws;
    auto carve = [&](size_t bytes) {
        char* p = w;
        w += (bytes + 255) & ~(size_t)255;
        return p;
    };
    // zeroed region first: cnt | stats0 | stats1 | ticket0 | ticket1
    int*   cnt     = (int*)  carve((size_t)N_ * 4);
    float* stats0  = (float*)carve(256 * 4);
    float* stats1  = (float*)carve(256 * 4);
    unsigned int* ticket0 = (unsigned int*)carve(256);
    unsigned int* ticket1 = (unsigned int*)carve(256);
    char*  zend    = w;
    float* dinv    = (float*)carve((size_t)N_ * 4);
    int*   rowptr  = (int*)  carve((size_t)(N_ + 1) * 4);
    int*   gcursor = (int*)  carve(512 * 4);
    int*   partials= (int*)  carve(1024 * 4);
    unsigned int* csr = (unsigned int*)carve((size_t)E_ * 4);
    uint2* binned  = (uint2*)carve((size_t)E_ * 8);
    float* sc0     = (float*)carve(128 * 4);
    float* sh0     = (float*)carve(128 * 4);
    float* sc1     = (float*)carve(128 * 4);
    float* sh1     = (float*)carve(128 * 4);
    unsigned short* Mbf = (unsigned short*)carve((size_t)N_ * 128 * 2);
    unsigned short* Hb  = (unsigned short*)carve((size_t)N_ * 128 * 2);

    const int gGemm = (N_ + 127) / 128;
    const int gGath = ((N_ + 3) / 4) * 4;          // 4 slabs x (N/4 nodes)
    const int nb    = (N_ + 1023) / 1024;
    const int nbk   = (N_ + 127) / 128;            // buckets (<=512)
    const int gBin  = (E_ + BCHUNK - 1) / BCHUNK;

    // ---- graph preprocessing ----
    hipMemsetAsync(cnt, 0, (size_t)(zend - (char*)cnt), stream);
    deg_count<<<(E_ + 255) / 256, 256, 0, stream>>>(ei, cnt, E_);
    scan_blocks<<<nb, 1024, 0, stream>>>(cnt, dinv, rowptr, partials, N_);
    scan_partials<<<1, 1024, 0, stream>>>(partials, rowptr + N_, nb);
    scan_add<<<(N_ + 255) / 256, 256, 0, stream>>>(rowptr, gcursor, partials, N_);
    bin_edges<<<gBin, 256, 0, stream>>>(ei, dinv, gcursor, binned, E_);
    place_edges<<<nbk, 256, 0, stream>>>(binned, rowptr, csr, N_);

    // ---- layer 0 ----
    gemm_mfma<false, false, false><<<gGemm, 256, 0, stream>>>(
        x, W0, nullptr, nullptr, nullptr, Mbf, N_);
    gather_q<false><<<gGath, 256, 0, stream>>>(Mbf, rowptr, csr, dinv, Hb, N_);
    bn_stats<<<512, 256, 0, stream>>>(Hb, stats0, g0, b0, sc0, sh0, ticket0, N_);

    // ---- layer 1 (BN0+ReLU fused into A-frag unpack) ----
    gemm_mfma<true, true, false><<<gGemm, 256, 0, stream>>>(
        Hb, W1, nullptr, sc0, sh0, Mbf, N_);
    gather_q<false><<<gGath, 256, 0, stream>>>(Mbf, rowptr, csr, dinv, Hb, N_);
    bn_stats<<<512, 256, 0, stream>>>(Hb, stats1, g1, b1, sc1, sh1, ticket1, N_);

    // ---- heads (BN1+ReLU fused): Mh = relu(BN(Hb)) @ [Wmu|Wlog]; out = A^ Mh
    gemm_mfma<true, true, true><<<gGemm, 256, 0, stream>>>(
        Hb, Wmu, Wlog, sc1, sh1, Mbf, N_);
    gather_q<true><<<gGath, 256, 0, stream>>>(Mbf, rowptr, csr, dinv, out, N_);
}

// Round 12
// 259.807 us; speedup vs baseline: 1.5322x; 1.5322x over previous
//
#include <hip/hip_runtime.h>
#include <hip/hip_bf16.h>

// ---------------------------------------------------------------------------
// GCN-VGAE encoder. Round 12: revert to R9 structure (row-major activations,
// full-row 64-lane gather waves) — R10/R11 proved slab locality costs more in
// lost memory-level parallelism than it saves in traffic (L3 ~6TB/s is not
// the binding constraint; lines-in-flight per wave is). Gather edge loop now
// unrolled x8 (32 lines in flight/wave, was 16).
// Pipeline: deg -> scan(+dinv) -> bin/place CSR sort ->
//   gemm0(x f32,W0)->Mbf -> gather->Hb -> bn_stats(+coef, ticket)
//   gemm1(Hb bn+relu,W1)->Mbf -> gather->Hb -> bn_stats(+coef, ticket)
//   gemmH(Hb bn+relu,[Wmu|Wlog])->Mbf -> gather->d_out (f32 split)
// ---------------------------------------------------------------------------

using short8 = __attribute__((ext_vector_type(8))) short;
using f32x4  = __attribute__((ext_vector_type(4))) float;

static __device__ __forceinline__ unsigned short f2bf(float f) {
    __hip_bfloat16 h = __float2bfloat16(f);
    return *reinterpret_cast<unsigned short*>(&h);
}
static __device__ __forceinline__ float bf_lo(unsigned int u) {
    return __uint_as_float(u << 16);
}
static __device__ __forceinline__ float bf_hi(unsigned int u) {
    return __uint_as_float(u & 0xffff0000u);
}
static __device__ __forceinline__ float bf2f(unsigned short u) {
    return __uint_as_float((unsigned int)u << 16);
}

__global__ __launch_bounds__(256)
void deg_count(const int* __restrict__ ei, int* __restrict__ cnt, int E_) {
    int e = blockIdx.x * 256 + threadIdx.x;
    if (e < E_) atomicAdd(&cnt[ei[E_ + e]], 1);   // row 1 = dst
}

// ---- hierarchical exclusive scan (dinv fused): cnt[0..n) -> rowptr[0..n] ----
__global__ __launch_bounds__(1024)
void scan_blocks(const int* __restrict__ cnt, float* __restrict__ dinv,
                 int* __restrict__ rowptr, int* __restrict__ partials, int n) {
    __shared__ int ls[1024];
    int tid = threadIdx.x;
    int i = blockIdx.x * 1024 + tid;
    int v = (i < n) ? cnt[i] : 0;
    if (i < n) dinv[i] = rsqrtf((float)v + 1.0f);
    ls[tid] = v;
    __syncthreads();
    #pragma unroll
    for (int off = 1; off < 1024; off <<= 1) {
        int t = (tid >= off) ? ls[tid - off] : 0;
        __syncthreads();
        ls[tid] += t;
        __syncthreads();
    }
    if (i < n) rowptr[i] = ls[tid] - v;           // local exclusive
    if (tid == 1023) partials[blockIdx.x] = ls[1023];
}

__global__ __launch_bounds__(1024)
void scan_partials(int* __restrict__ partials, int* __restrict__ rowptr_n,
                   int nb) {
    __shared__ int ls[1024];
    int tid = threadIdx.x;
    int v = (tid < nb) ? partials[tid] : 0;
    ls[tid] = v;
    __syncthreads();
    #pragma unroll
    for (int off = 1; off < 1024; off <<= 1) {
        int t = (tid >= off) ? ls[tid - off] : 0;
        __syncthreads();
        ls[tid] += t;
        __syncthreads();
    }
    if (tid < nb) partials[tid] = ls[tid] - v;    // exclusive block offsets
    if (tid == 1023) *rowptr_n = ls[1023];        // rowptr[n] = E
}

// add block offsets; also seed per-bucket claim cursors gcursor[b]=rowptr[b*128]
__global__ __launch_bounds__(256)
void scan_add(int* __restrict__ rowptr, int* __restrict__ gcursor,
              const int* __restrict__ partials, int n) {
    int i = blockIdx.x * 256 + threadIdx.x;
    if (i < n) {
        int v = rowptr[i] + partials[i >> 10];
        rowptr[i] = v;
        if ((i & 127) == 0) gcursor[i >> 7] = v;
    }
}

// ---- CSR build pass 1: bin edges into 128-node buckets ----
#define BCHUNK 4096
__global__ __launch_bounds__(256)
void bin_edges(const int* __restrict__ ei, const float* __restrict__ dinv,
               int* __restrict__ gcursor, uint2* __restrict__ binned, int E_) {
    __shared__ int hist[512];
    __shared__ int gbase[512];
    __shared__ int cur[512];
    const int tid = threadIdx.x;
    const int e0 = blockIdx.x * BCHUNK;

    #pragma unroll
    for (int q = 0; q < 2; ++q) hist[q * 256 + tid] = 0;
    __syncthreads();

    for (int i = tid; i < BCHUNK; i += 256) {
        int e = e0 + i;
        if (e < E_) atomicAdd(&hist[ei[E_ + e] >> 7], 1);
    }
    __syncthreads();

    #pragma unroll
    for (int q = 0; q < 2; ++q) {
        int b = q * 256 + tid;
        int c = hist[b];
        gbase[b] = c ? atomicAdd(&gcursor[b], c) : 0;
        cur[b] = 0;
    }
    __syncthreads();

    for (int i = tid; i < BCHUNK; i += 256) {
        int e = e0 + i;
        if (e >= E_) continue;
        int s = ei[e], d = ei[E_ + e];
        float coef = dinv[s] * dinv[d];
        unsigned int cb = (__float_as_uint(coef) + 0x8000u) >> 16;  // RN bf16
        unsigned int entry = ((unsigned int)s << 15) | (cb & 0x7fffu);
        int b = d >> 7;
        int p = gbase[b] + atomicAdd(&cur[b], 1);
        binned[p] = make_uint2(entry, (unsigned int)(d & 127));
    }
}

// ---- CSR build pass 2: exact placement within each bucket ----
__global__ __launch_bounds__(256)
void place_edges(const uint2* __restrict__ binned, const int* __restrict__ rowptr,
                 unsigned int* __restrict__ csr, int n) {
    __shared__ int cur[128];
    const int tid = threadIdx.x;
    const int n0 = blockIdx.x * 128;
    const int nn = min(128, n - n0);
    if (tid < nn) cur[tid] = rowptr[n0 + tid];
    __syncthreads();
    const int beg = rowptr[n0];
    const int end = rowptr[min(n0 + 128, n)];
    for (int i = beg + tid; i < end; i += 256) {
        uint2 v = binned[i];
        int p = atomicAdd(&cur[v.y], 1);
        csr[p] = v.x;
    }
}

// ---------------------------------------------------------------------------
// MFMA GEMM: Y(bf16 N x 128 row-major) = act(X) @ W, K=128.
// XBF: X bf16 else f32. FUSE_BN: act = relu(v*sc+sh).
// SPLIT_W: W = [Wa | Wb] column-concat (each 128x64 f32).
// ---------------------------------------------------------------------------
template<bool XBF, bool FUSE_BN, bool SPLIT_W>
__global__ __launch_bounds__(256)
void gemm_mfma(const void* __restrict__ Xv, const float* __restrict__ Wa,
               const float* __restrict__ Wb, const float* __restrict__ sc,
               const float* __restrict__ sh, unsigned short* __restrict__ Y,
               int nRows) {
    __shared__ unsigned short wt[128 * 128];  // [c][k] bf16, k XOR-swizzled

    const int tid = threadIdx.x;

    #pragma unroll
    for (int it = 0; it < 16; ++it) {
        int flat4 = it * 256 + tid;          // float4 index over 16384 floats
        int k  = flat4 >> 5;
        int c0 = (flat4 & 31) * 4;
        const float* srcp;
        if (!SPLIT_W) srcp = Wa + k * 128 + c0;
        else          srcp = (c0 < 64) ? (Wa + k * 64 + c0)
                                       : (Wb + k * 64 + (c0 - 64));
        float4 v = *(const float4*)srcp;
        float vv[4] = {v.x, v.y, v.z, v.w};
        #pragma unroll
        for (int j = 0; j < 4; ++j) {
            int c = c0 + j;
            wt[c * 128 + (k ^ ((c & 7) << 3))] = f2bf(vv[j]);
        }
    }
    __syncthreads();

    const int lane = tid & 63;
    const int wv   = tid >> 6;
    const int lm   = lane & 15;              // frag row (A) / col (B,D)
    const int lg   = lane >> 4;              // k-group
    const int row0 = blockIdx.x * 128 + wv * 32;

    f32x4 acc[2][8] = {};

    #pragma unroll
    for (int ks = 0; ks < 4; ++ks) {
        const int k0 = ks * 32 + lg * 8;

        short8 a[2];
        #pragma unroll
        for (int mf = 0; mf < 2; ++mf) {
            int r = row0 + mf * 16 + lm;
            if (r < nRows) {
                if (XBF) {
                    a[mf] = *(const short8*)((const unsigned short*)Xv +
                                             (size_t)r * 128 + k0);
                    if (FUSE_BN) {
                        float4 s0 = *(const float4*)(sc + k0);
                        float4 s1 = *(const float4*)(sc + k0 + 4);
                        float4 h0 = *(const float4*)(sh + k0);
                        float4 h1 = *(const float4*)(sh + k0 + 4);
                        float sv[8] = {s0.x, s0.y, s0.z, s0.w, s1.x, s1.y, s1.z, s1.w};
                        float hv[8] = {h0.x, h0.y, h0.z, h0.w, h1.x, h1.y, h1.z, h1.w};
                        #pragma unroll
                        for (int j = 0; j < 8; ++j) {
                            float v = bf2f((unsigned short)a[mf][j]);
                            v = fmaxf(v * sv[j] + hv[j], 0.f);
                            a[mf][j] = (short)f2bf(v);
                        }
                    }
                } else {
                    const float* xp = (const float*)Xv + (size_t)r * 128 + k0;
                    float4 p0 = *(const float4*)xp;
                    float4 p1 = *(const float4*)(xp + 4);
                    float pv[8] = {p0.x, p0.y, p0.z, p0.w, p1.x, p1.y, p1.z, p1.w};
                    #pragma unroll
                    for (int j = 0; j < 8; ++j) a[mf][j] = (short)f2bf(pv[j]);
                }
            } else {
                a[mf] = short8{};
            }
        }

        #pragma unroll
        for (int f = 0; f < 8; ++f) {
            int c = f * 16 + lm;
            short8 b = *(const short8*)&wt[c * 128 + (k0 ^ ((c & 7) << 3))];
            acc[0][f] = __builtin_amdgcn_mfma_f32_16x16x32_bf16(a[0], b, acc[0][f], 0, 0, 0);
            acc[1][f] = __builtin_amdgcn_mfma_f32_16x16x32_bf16(a[1], b, acc[1][f], 0, 0, 0);
        }
    }

    #pragma unroll
    for (int mf = 0; mf < 2; ++mf) {
        #pragma unroll
        for (int reg = 0; reg < 4; ++reg) {
            int r = row0 + mf * 16 + lg * 4 + reg;
            if (r >= nRows) continue;
            #pragma unroll
            for (int f = 0; f < 8; ++f)
                Y[(size_t)r * 128 + f * 16 + lm] = f2bf(acc[mf][f][reg]);
        }
    }
}

// O[d,:] = dinv[d]^2 * M[d,:] + sum_k coef_k * M[src_k,:]   (M bf16)
// one wave per dst row; lane owns channels {2l,2l+1}; unroll x8 (32 lines
// in flight per wave — MLP is the binding constraint per R10/R11).
template<bool TO_OUT>
__global__ __launch_bounds__(256)
void gather_bf(const unsigned short* __restrict__ M,
               const int* __restrict__ rowptr,
               const unsigned int* __restrict__ csr,
               const float* __restrict__ dinv, void* __restrict__ O, int n) {
    int wid  = (blockIdx.x * 256 + threadIdx.x) >> 6;
    int lane = threadIdx.x & 63;
    if (wid >= n) return;
    const unsigned int* m2 = (const unsigned int*)M;   // 2 bf16 per uint

    float di = dinv[wid];
    unsigned int su = m2[(size_t)wid * 64 + lane];
    float c = di * di;
    float ax0 = bf_lo(su) * c, ay0 = bf_hi(su) * c;
    float ax1 = 0.f, ay1 = 0.f, ax2 = 0.f, ay2 = 0.f, ax3 = 0.f, ay3 = 0.f;
    float ax4 = 0.f, ay4 = 0.f, ax5 = 0.f, ay5 = 0.f, ax6 = 0.f, ay6 = 0.f;
    float ax7 = 0.f, ay7 = 0.f;

    int beg = __builtin_amdgcn_readfirstlane(rowptr[wid]);
    int end = __builtin_amdgcn_readfirstlane(rowptr[wid + 1]);

    int k = beg;
    for (; k + 7 < end; k += 8) {
        unsigned int e0 = csr[k],     e1 = csr[k + 1];
        unsigned int e2 = csr[k + 2], e3 = csr[k + 3];
        unsigned int e4 = csr[k + 4], e5 = csr[k + 5];
        unsigned int e6 = csr[k + 6], e7 = csr[k + 7];
        unsigned int u0 = m2[(size_t)(e0 >> 15) * 64 + lane];
        unsigned int u1 = m2[(size_t)(e1 >> 15) * 64 + lane];
        unsigned int u2 = m2[(size_t)(e2 >> 15) * 64 + lane];
        unsigned int u3 = m2[(size_t)(e3 >> 15) * 64 + lane];
        unsigned int u4 = m2[(size_t)(e4 >> 15) * 64 + lane];
        unsigned int u5 = m2[(size_t)(e5 >> 15) * 64 + lane];
        unsigned int u6 = m2[(size_t)(e6 >> 15) * 64 + lane];
        unsigned int u7 = m2[(size_t)(e7 >> 15) * 64 + lane];
        float w0 = __uint_as_float((e0 & 0x7fffu) << 16);
        float w1 = __uint_as_float((e1 & 0x7fffu) << 16);
        float w2 = __uint_as_float((e2 & 0x7fffu) << 16);
        float w3 = __uint_as_float((e3 & 0x7fffu) << 16);
        float w4 = __uint_as_float((e4 & 0x7fffu) << 16);
        float w5 = __uint_as_float((e5 & 0x7fffu) << 16);
        float w6 = __uint_as_float((e6 & 0x7fffu) << 16);
        float w7 = __uint_as_float((e7 & 0x7fffu) << 16);
        ax0 += w0 * bf_lo(u0); ay0 += w0 * bf_hi(u0);
        ax1 += w1 * bf_lo(u1); ay1 += w1 * bf_hi(u1);
        ax2 += w2 * bf_lo(u2); ay2 += w2 * bf_hi(u2);
        ax3 += w3 * bf_lo(u3); ay3 += w3 * bf_hi(u3);
        ax4 += w4 * bf_lo(u4); ay4 += w4 * bf_hi(u4);
        ax5 += w5 * bf_lo(u5); ay5 += w5 * bf_hi(u5);
        ax6 += w6 * bf_lo(u6); ay6 += w6 * bf_hi(u6);
        ax7 += w7 * bf_lo(u7); ay7 += w7 * bf_hi(u7);
    }
    for (; k < end; ++k) {
        unsigned int e0 = csr[k];
        unsigned int u0 = m2[(size_t)(e0 >> 15) * 64 + lane];
        float w0 = __uint_as_float((e0 & 0x7fffu) << 16);
        ax0 += w0 * bf_lo(u0); ay0 += w0 * bf_hi(u0);
    }
    float ax = ((ax0 + ax1) + (ax2 + ax3)) + ((ax4 + ax5) + (ax6 + ax7));
    float ay = ((ay0 + ay1) + (ay2 + ay3)) + ((ay4 + ay5) + (ay6 + ay7));

    if (!TO_OUT) {
        unsigned int o = (unsigned int)f2bf(ax) | ((unsigned int)f2bf(ay) << 16);
        ((unsigned int*)O)[(size_t)wid * 64 + lane] = o;
    } else {
        float* Of = (float*)O;
        float* dst = (lane < 32)
            ? Of + (size_t)wid * 64 + 2 * lane
            : Of + (size_t)n * 64 + (size_t)wid * 64 + 2 * (lane - 32);
        *(float2*)dst = make_float2(ax, ay);
    }
}

// column sums/sumsq over N rows of bf16 H + FUSED bn_coef via last-block
// ticket (sync before ticket; AGENT-scope loads in last block).
__global__ __launch_bounds__(256)
void bn_stats(const unsigned short* __restrict__ H, float* __restrict__ stats,
              const float* __restrict__ gamma, const float* __restrict__ beta,
              float* __restrict__ sc, float* __restrict__ sh,
              unsigned int* __restrict__ ticket, int n) {
    const uint4* h4 = (const uint4*)H;            // 8 bf16 per uint4, 16/row
    const int tid = threadIdx.x;
    const int cg = tid & 15;                      // channel group (8 ch)
    const int rg = tid >> 4;                      // row-in-block 0..15
    float s[8] = {}, q[8] = {};
    for (int r = blockIdx.x * 16 + rg; r < n; r += gridDim.x * 16) {
        uint4 u = h4[(size_t)r * 16 + cg];        // coalesced 4KB/block/iter
        float v[8] = {bf_lo(u.x), bf_hi(u.x), bf_lo(u.y), bf_hi(u.y),
                      bf_lo(u.z), bf_hi(u.z), bf_lo(u.w), bf_hi(u.w)};
        #pragma unroll
        for (int j = 0; j < 8; ++j) { s[j] += v[j]; q[j] += v[j] * v[j]; }
    }
    __shared__ float ls[256][17];                 // pad to dodge bank aliasing
    #pragma unroll
    for (int j = 0; j < 8; ++j) { ls[tid][j] = s[j]; ls[tid][8 + j] = q[j]; }
    __syncthreads();
    if (tid < 128) {
        int cgrp = tid >> 3, j = tid & 7;
        float S = 0.f, Q = 0.f;
        #pragma unroll
        for (int g = 0; g < 16; ++g) {
            S += ls[(g << 4) | cgrp][j];
            Q += ls[(g << 4) | cgrp][8 + j];
        }
        atomicAdd(&stats[tid], S);
        atomicAdd(&stats[128 + tid], Q);
    }
    // drain ALL waves' stats atomics before publishing this block's ticket
    __syncthreads();
    __shared__ int lastFlag;
    if (tid == 0) {
        __threadfence();
        unsigned int t = atomicAdd(ticket, 1u);
        lastFlag = (t == gridDim.x - 1);
    }
    __syncthreads();
    if (lastFlag && tid < 128) {
        float Ssum = __hip_atomic_load(&stats[tid], __ATOMIC_RELAXED,
                                       __HIP_MEMORY_SCOPE_AGENT);
        float Qsum = __hip_atomic_load(&stats[128 + tid], __ATOMIC_RELAXED,
                                       __HIP_MEMORY_SCOPE_AGENT);
        float inv_n = 1.0f / (float)n;
        float mean = Ssum * inv_n;
        float var  = Qsum * inv_n - mean * mean;
        float sv = rsqrtf(var + 1e-5f) * gamma[tid];
        sc[tid] = sv;
        sh[tid] = beta[tid] - mean * sv;
    }
}

extern "C" void kernel_launch(void* const* d_in, const int* in_sizes, int n_in,
                              void* d_out, int out_size, void* d_ws, size_t ws_size,
                              hipStream_t stream) {
    const float* x    = (const float*)d_in[0];
    const int*   ei   = (const int*)d_in[1];
    const float* W0   = (const float*)d_in[2];
    const float* W1   = (const float*)d_in[3];
    const float* Wmu  = (const float*)d_in[4];
    const float* Wlog = (const float*)d_in[5];
    const float* g0   = (const float*)d_in[6];
    const float* b0   = (const float*)d_in[7];
    const float* g1   = (const float*)d_in[8];
    const float* b1   = (const float*)d_in[9];

    const int N_ = in_sizes[0] / 128;
    const int E_ = in_sizes[1] / 2;
    float* out = (float*)d_out;

    char* w = (char*)d_ws;
    auto carve = [&](size_t bytes) {
        char* p = w;
        w += (bytes + 255) & ~(size_t)255;
        return p;
    };
    // zeroed region first: cnt | stats0 | stats1 | ticket0 | ticket1
    int*   cnt     = (int*)  carve((size_t)N_ * 4);
    float* stats0  = (float*)carve(256 * 4);
    float* stats1  = (float*)carve(256 * 4);
    unsigned int* ticket0 = (unsigned int*)carve(256);
    unsigned int* ticket1 = (unsigned int*)carve(256);
    char*  zend    = w;
    float* dinv    = (float*)carve((size_t)N_ * 4);
    int*   rowptr  = (int*)  carve((size_t)(N_ + 1) * 4);
    int*   gcursor = (int*)  carve(512 * 4);
    int*   partials= (int*)  carve(1024 * 4);
    unsigned int* csr = (unsigned int*)carve((size_t)E_ * 4);
    uint2* binned  = (uint2*)carve((size_t)E_ * 8);
    float* sc0     = (float*)carve(128 * 4);
    float* sh0     = (float*)carve(128 * 4);
    float* sc1     = (float*)carve(128 * 4);
    float* sh1     = (float*)carve(128 * 4);
    unsigned short* Mbf = (unsigned short*)carve((size_t)N_ * 128 * 2);
    unsigned short* Hb  = (unsigned short*)carve((size_t)N_ * 128 * 2);

    const int gGemm = (N_ + 127) / 128;
    const int gGath = (N_ * 64 + 255) / 256;       // one wave per node
    const int nb    = (N_ + 1023) / 1024;
    const int nbk   = (N_ + 127) / 128;            // buckets (<=512)
    const int gBin  = (E_ + BCHUNK - 1) / BCHUNK;

    // ---- graph preprocessing ----
    hipMemsetAsync(cnt, 0, (size_t)(zend - (char*)cnt), stream);
    deg_count<<<(E_ + 255) / 256, 256, 0, stream>>>(ei, cnt, E_);
    scan_blocks<<<nb, 1024, 0, stream>>>(cnt, dinv, rowptr, partials, N_);
    scan_partials<<<1, 1024, 0, stream>>>(partials, rowptr + N_, nb);
    scan_add<<<(N_ + 255) / 256, 256, 0, stream>>>(rowptr, gcursor, partials, N_);
    bin_edges<<<gBin, 256, 0, stream>>>(ei, dinv, gcursor, binned, E_);
    place_edges<<<nbk, 256, 0, stream>>>(binned, rowptr, csr, N_);

    // ---- layer 0 ----
    gemm_mfma<false, false, false><<<gGemm, 256, 0, stream>>>(
        x, W0, nullptr, nullptr, nullptr, Mbf, N_);
    gather_bf<false><<<gGath, 256, 0, stream>>>(Mbf, rowptr, csr, dinv, Hb, N_);
    bn_stats<<<512, 256, 0, stream>>>(Hb, stats0, g0, b0, sc0, sh0, ticket0, N_);

    // ---- layer 1 (BN0+ReLU fused into A-frag unpack) ----
    gemm_mfma<true, true, false><<<gGemm, 256, 0, stream>>>(
        Hb, W1, nullptr, sc0, sh0, Mbf, N_);
    gather_bf<false><<<gGath, 256, 0, stream>>>(Mbf, rowptr, csr, dinv, Hb, N_);
    bn_stats<<<512, 256, 0, stream>>>(Hb, stats1, g1, b1, sc1, sh1, ticket1, N_);

    // ---- heads (BN1+ReLU fused): Mh = relu(BN(Hb)) @ [Wmu|Wlog]; out = A^ Mh
    gemm_mfma<true, true, true><<<gGemm, 256, 0, stream>>>(
        Hb, Wmu, Wlog, sc1, sh1, Mbf, N_);
    gather_bf<true><<<gGath, 256, 0, stream>>>(Mbf, rowptr, csr, dinv, out, N_);
}